// Round 7
// baseline (1658.609 us; speedup 1.0000x reference)
//
#include <hip/hip_runtime.h>
#include <cstddef>
#include <cstdint>

// Problem constants (fixed by reference): B=64, T=128, C=4096, H=32, HS=128
#define NB 64
#define NH 32
#define NT 128
#define NHS 128
#define NC 4096
#define SCALE 0.17677669529663687f  // 32^-0.5
#define SLD 136                      // bf16 leading dim for attention score tile

typedef __bf16 bf16_t;
typedef __bf16 bf16x8 __attribute__((ext_vector_type(8)));
typedef float  f32x4  __attribute__((ext_vector_type(4)));

// Async global->LDS, 16B per lane. LDS dest must be wave-uniform base + lane*16.
__device__ __forceinline__ void load_lds16(const bf16_t* g, bf16_t* l) {
    __builtin_amdgcn_global_load_lds(
        (const __attribute__((address_space(1))) char*)g,
        (__attribute__((address_space(3))) char*)l,
        16, 0, 0);
}

#define SBAR() __builtin_amdgcn_sched_barrier(0)
#define BARRIER() __builtin_amdgcn_s_barrier()
#define LGKM0() asm volatile("s_waitcnt lgkmcnt(0)" ::: "memory")

// ---------------------------------------------------------------------------
// Conversion: fp32 -> bf16, 8 elements/thread
// ---------------------------------------------------------------------------
__global__ __launch_bounds__(256) void cvt_bf16_kernel(
    const float* __restrict__ in, bf16_t* __restrict__ out, int n8)
{
    int i = blockIdx.x * 256 + threadIdx.x;
    if (i >= n8) return;
    const float4* p = (const float4*)in + (size_t)i * 2;
    float4 a = p[0], b = p[1];
    bf16x8 o;
    o[0] = (bf16_t)a.x; o[1] = (bf16_t)a.y; o[2] = (bf16_t)a.z; o[3] = (bf16_t)a.w;
    o[4] = (bf16_t)b.x; o[5] = (bf16_t)b.y; o[6] = (bf16_t)b.z; o[7] = (bf16_t)b.w;
    ((bf16x8*)out)[i] = o;
}

// ---------------------------------------------------------------------------
// Conversion + transpose: w [H][C][HS] fp32 -> wT [H][HS][C] bf16.
// ---------------------------------------------------------------------------
__global__ __launch_bounds__(256) void cvt_w_transpose_kernel(
    const float* __restrict__ wq, const float* __restrict__ wk, const float* __restrict__ wv,
    bf16_t* __restrict__ qt, bf16_t* __restrict__ kt, bf16_t* __restrict__ vt)
{
    const float* w; bf16_t* o;
    if (blockIdx.y == 0)      { w = wq; o = qt; }
    else if (blockIdx.y == 1) { w = wk; o = kt; }
    else                      { w = wv; o = vt; }
    const int h   = blockIdx.x >> 7;
    const int rem = blockIdx.x & 127;
    const int c0  = (rem >> 1) * 64;
    const int s0  = (rem & 1) * 64;
    const float* W = w + (size_t)h * NC * NHS;
    bf16_t* O = o + (size_t)h * NHS * NC;

    __shared__ float t[64][65];
    const int tid = threadIdx.x;
    #pragma unroll
    for (int it = 0; it < 16; ++it) {
        int idx = it * 256 + tid;
        int r = idx >> 6, cc = idx & 63;
        t[r][cc] = W[(size_t)(c0 + r) * NHS + s0 + cc];
    }
    __syncthreads();
    #pragma unroll
    for (int it = 0; it < 16; ++it) {
        int idx = it * 256 + tid;
        int sr = idx >> 6, cr = idx & 63;
        O[(size_t)(s0 + sr) * NC + c0 + cr] = (bf16_t)t[cr][sr];
    }
}

// ---------------------------------------------------------------------------
// 256x256 tile GEMM core, K = 4096 (ld = NC), 8 waves (2M x 4N), BK = 64.
// 4-phase/K-tile schedule with QUADRANT-matched A staging (fixes R5 race):
//   a0 (ih=0) reads slabs {0,2}; a1 (ih=1) reads slabs {1,3}. A stage units
//   are s{0,2} / s{1,3} so a stage never overwrites rows a later phase of the
//   SAME tile still reads.
//   ph1: read a0; stage Ao <- A(t+1) s{1,3}    (last read tile t-1 ph3)
//   ph2: read b1; stage Ac <- A(t+2) s{0,2}    (a0 done ph1; disjoint from a1)
//   ph3: read a1; stage Bc <- B(t+2) h0        (all B reads of t done ph2)
//   ph4: stage Bc <- B(t+2) h1; vmcnt(6); MFMA a1xb0c; pre-read b0(t+1) @ Bo
// Steady state: 6 loads in flight, vmcnt(6) once per tile retires exactly
// tile t+1; never 0 until t=62 tail drain. MFMA quadrants a0b0->a0b1->a1b1->
// a1b0 (register reuse, balanced 8/4/8/4 ds_reads).
// XOR-swizzled LDS via pre-swizzled global source (0 bank conflicts).
// LDS: 2 x (A 32K + B 32K) = 128 KiB.
// ---------------------------------------------------------------------------
#define KT_EL 16384   // K-tile elements: 256 rows x 64 cols

__device__ __forceinline__ void gemm256_core(
    const bf16_t* __restrict__ A, const bf16_t* __restrict__ BT, f32x4 acc[8][4])
{
    __shared__ __align__(16) bf16_t As[2 * KT_EL];
    __shared__ __align__(16) bf16_t Bs[2 * KT_EL];

    const int tid  = threadIdx.x;
    const int lane = tid & 63;
    const int w    = tid >> 6;
    const int wr   = w >> 2;   // 0..1 (M half)
    const int wc   = w & 3;    // 0..3 (N quarter)

    // staging: slab j (64 rows), thread covers 8 contiguous elements; LDS dest
    // linear, global source column pre-swizzled: LDS(r,c) = G(r, c^((r&7)<<3)).
    const int srow  = tid >> 3;
    const int scol  = ((tid & 7) * 8) ^ (((tid >> 3) & 7) << 3);
    const int sslot = tid * 8;

    // fragment read offsets (elements within one 16384-el K-tile)
    const int frow = lane & 15;
    const int fk   = (lane >> 4) * 8;
    int aoff[2][2][4];   // [ks][ih][q] : row = wr*128 + ih*64 + q*16 + frow
    #pragma unroll
    for (int ks = 0; ks < 2; ++ks)
        #pragma unroll
        for (int ih = 0; ih < 2; ++ih)
            #pragma unroll
            for (int q = 0; q < 4; ++q) {
                int r = wr * 128 + ih * 64 + q * 16 + frow;
                aoff[ks][ih][q] = r * 64 + ((ks * 32 + fk) ^ ((r & 7) << 3));
            }
    int boff[2][4];      // [ks][n] : row = wc*64 + n*16 + frow
    #pragma unroll
    for (int ks = 0; ks < 2; ++ks)
        #pragma unroll
        for (int n = 0; n < 4; ++n) {
            int r = wc * 64 + n * 16 + frow;
            boff[ks][n] = r * 64 + ((ks * 32 + fk) ^ ((r & 7) << 3));
        }

    // stage ONE slab j (64 rows), 1 load/thread
    auto stageS = [&](const bf16_t* __restrict__ G, int j, int k0, bf16_t* dst) {
        load_lds16(G + (size_t)(j * 64 + srow) * NC + (k0 + scol),
                   dst + j * 4096 + sslot);
    };
    // stage one contiguous half-tile (slabs {2h, 2h+1}), 2 loads/thread
    auto stageH = [&](const bf16_t* __restrict__ G, int half, int k0, bf16_t* dst) {
        #pragma unroll
        for (int jj = 0; jj < 2; ++jj)
            stageS(G, half * 2 + jj, k0, dst);
    };

    // Prologue: tile0 full (buf0) + {A(1)s{0,2}, B(1)h0, B(1)h1} (buf1) = 14.
    stageH(A,  0, 0, As);  stageH(A,  1, 0, As);
    stageH(BT, 0, 0, Bs);  stageH(BT, 1, 0, Bs);
    stageS(A, 0, 64, As + KT_EL);
    stageS(A, 2, 64, As + KT_EL);
    stageH(BT, 0, 64, Bs + KT_EL);
    stageH(BT, 1, 64, Bs + KT_EL);
    asm volatile("s_waitcnt vmcnt(6)" ::: "memory");  // tile0 resident; 6 in flight
    BARRIER();
    SBAR();

    // carried b0 fragments of the CURRENT tile (tile 0 from buf0)
    bf16x8 b0c[2][2];
    #pragma unroll
    for (int ks = 0; ks < 2; ++ks)
        #pragma unroll
        for (int n = 0; n < 2; ++n)
            b0c[ks][n] = *(const bf16x8*)(Bs + boff[ks][n]);

    #pragma unroll 1
    for (int t = 0; t < 64; ++t) {
        const int p = t & 1;
        bf16_t* Ac = As + p * KT_EL;
        bf16_t* Bc = Bs + p * KT_EL;
        bf16_t* Ao = As + (p ^ 1) * KT_EL;
        bf16_t* Bo = Bs + (p ^ 1) * KT_EL;
        const bool s1 = (t < 63);   // stage for tile t+1 / read next b0
        const bool s2 = (t < 62);   // stages for tile t+2
        const int k1 = (t + 1) * 64;
        const int k2 = (t + 2) * 64;

        bf16x8 a0[2][4], a1[2][4], b1[2][2], b0n[2][2];

        // ---- ph1: read a0 (slabs 0,2); stage Ao <- A(t+1) s{1,3}; a0 x b0c --
        #pragma unroll
        for (int ks = 0; ks < 2; ++ks)
            #pragma unroll
            for (int q = 0; q < 4; ++q)
                a0[ks][q] = *(const bf16x8*)(Ac + aoff[ks][0][q]);
        if (s1) { stageS(A, 1, k1, Ao); stageS(A, 3, k1, Ao); }
        SBAR();
        BARRIER();
        LGKM0();
        SBAR();
        __builtin_amdgcn_s_setprio(1);
        #pragma unroll
        for (int ks = 0; ks < 2; ++ks)
            #pragma unroll
            for (int q = 0; q < 4; ++q)
                #pragma unroll
                for (int n = 0; n < 2; ++n)
                    acc[q][n] = __builtin_amdgcn_mfma_f32_16x16x32_bf16(a0[ks][q], b0c[ks][n], acc[q][n], 0, 0, 0);
        __builtin_amdgcn_s_setprio(0);
        BARRIER();
        SBAR();

        // ---- ph2: read b1; stage Ac <- A(t+2) s{0,2}; a0 x b1 ----
        #pragma unroll
        for (int ks = 0; ks < 2; ++ks)
            #pragma unroll
            for (int n = 0; n < 2; ++n)
                b1[ks][n] = *(const bf16x8*)(Bc + boff[ks][2 + n]);
        if (s2) { stageS(A, 0, k2, Ac); stageS(A, 2, k2, Ac); }
        SBAR();
        BARRIER();
        LGKM0();
        SBAR();
        __builtin_amdgcn_s_setprio(1);
        #pragma unroll
        for (int ks = 0; ks < 2; ++ks)
            #pragma unroll
            for (int q = 0; q < 4; ++q)
                #pragma unroll
                for (int n = 0; n < 2; ++n)
                    acc[q][2 + n] = __builtin_amdgcn_mfma_f32_16x16x32_bf16(a0[ks][q], b1[ks][n], acc[q][2 + n], 0, 0, 0);
        __builtin_amdgcn_s_setprio(0);
        BARRIER();
        SBAR();

        // ---- ph3: read a1 (slabs 1,3); stage Bc <- B(t+2) h0; a1 x b1 ----
        #pragma unroll
        for (int ks = 0; ks < 2; ++ks)
            #pragma unroll
            for (int q = 0; q < 4; ++q)
                a1[ks][q] = *(const bf16x8*)(Ac + aoff[ks][1][q]);
        if (s2) stageH(BT, 0, k2, Bc);
        SBAR();
        BARRIER();
        LGKM0();
        SBAR();
        __builtin_amdgcn_s_setprio(1);
        #pragma unroll
        for (int ks = 0; ks < 2; ++ks)
            #pragma unroll
            for (int q = 0; q < 4; ++q)
                #pragma unroll
                for (int n = 0; n < 2; ++n)
                    acc[4 + q][2 + n] = __builtin_amdgcn_mfma_f32_16x16x32_bf16(a1[ks][q], b1[ks][n], acc[4 + q][2 + n], 0, 0, 0);
        __builtin_amdgcn_s_setprio(0);
        BARRIER();
        SBAR();

        // ---- ph4: stage Bc <- B(t+2) h1; vmcnt(6); a1 x b0c; pre-read b0 ----
        if (s2) {
            stageH(BT, 1, k2, Bc);
            asm volatile("s_waitcnt vmcnt(6)" ::: "memory");
        } else if (t == 62) {
            asm volatile("s_waitcnt vmcnt(0)" ::: "memory");   // tail drain
        }
        SBAR();
        BARRIER();
        SBAR();
        __builtin_amdgcn_s_setprio(1);
        #pragma unroll
        for (int ks = 0; ks < 2; ++ks)
            #pragma unroll
            for (int q = 0; q < 4; ++q)
                #pragma unroll
                for (int n = 0; n < 2; ++n)
                    acc[4 + q][n] = __builtin_amdgcn_mfma_f32_16x16x32_bf16(a1[ks][q], b0c[ks][n], acc[4 + q][n], 0, 0, 0);
        __builtin_amdgcn_s_setprio(0);
        if (s1) {
            #pragma unroll
            for (int ks = 0; ks < 2; ++ks)
                #pragma unroll
                for (int n = 0; n < 2; ++n)
                    b0n[ks][n] = *(const bf16x8*)(Bo + boff[ks][n]);
        }
        SBAR();
        BARRIER();
        SBAR();
        if (s1) {
            #pragma unroll
            for (int ks = 0; ks < 2; ++ks)
                #pragma unroll
                for (int n = 0; n < 2; ++n)
                    b0c[ks][n] = b0n[ks][n];
        }
    }
}

// ---------------------------------------------------------------------------
// QKV as ONE GEMM: x[8192,4096] * Wcat[12288,4096]^T.  Wcat = wqT|wkT|wvT
// contiguous ([tensor][h][s][c]).  grid = 1536 blocks (32 mt x 48 nt),
// XCD-chunked swizzle.  q,k stored [bh][t][s]; v stored transposed [bh][s][t].
// ---------------------------------------------------------------------------
__global__ __launch_bounds__(512, 2) void qkv_gemm256_kernel(
    const bf16_t* __restrict__ xb, const bf16_t* __restrict__ wcat,
    bf16_t* __restrict__ q, bf16_t* __restrict__ k, bf16_t* __restrict__ v)
{
    const int bid = blockIdx.x;
    const int wg  = (bid & 7) * 192 + (bid >> 3);   // 1536 = 8 * 192, bijective
    const int mt  = wg / 48;
    const int nt  = wg - mt * 48;
    const int Mb  = mt << 8;
    const int Nb  = nt << 8;

    f32x4 acc[8][4] = {};
    gemm256_core(xb + (size_t)Mb * NC, wcat + (size_t)Nb * NC, acc);

    const int tid = threadIdx.x, lane = tid & 63, w = tid >> 6;
    const int wr = w >> 2, wc = w & 3;
    const int tens = Nb >> 12;                       // 0=q 1=k 2=v (uniform)
    bf16_t* const outp = (tens == 0) ? q : (tens == 1) ? k : v;
    const int colb = Nb + wc * 64 + (lane & 15);
    const int rowb = Mb + wr * 128 + ((lane >> 4) << 2);
    if (tens == 2) {
        // vT[s][u]: for fixed (i,n), r walks contiguous u -> pack 4 bf16 = 8B
        #pragma unroll
        for (int i = 0; i < 8; ++i) {
            const int m0 = rowb + i * 16;
            const int bb = m0 >> 7, tt0 = m0 & 127;
            #pragma unroll
            for (int n = 0; n < 4; ++n) {
                const int ng = colb + n * 16;
                const int hh = (ng >> 7) & 31, ss = ng & 127;
                const size_t base = (size_t)((bb << 5) + hh) << 14;
                bf16_t pk[4];
                #pragma unroll
                for (int r = 0; r < 4; ++r) pk[r] = (bf16_t)acc[i][n][r];
                *(uint64_t*)(outp + base + (size_t)ss * NT + tt0) = *(const uint64_t*)pk;
            }
        }
    } else {
        #pragma unroll
        for (int i = 0; i < 8; ++i)
            #pragma unroll
            for (int r = 0; r < 4; ++r) {
                const int m  = rowb + i * 16 + r;
                const int bb = m >> 7, tt = m & 127;
                #pragma unroll
                for (int n = 0; n < 4; ++n) {
                    const int ng = colb + n * 16;
                    const int hh = (ng >> 7) & 31, ss = ng & 127;
                    const size_t base = (size_t)((bb << 5) + hh) << 14;
                    outp[base + (size_t)tt * NHS + ss] = (bf16_t)acc[i][n][r];
                }
            }
    }
}

// ---------------------------------------------------------------------------
// Projection as ONE GEMM: attnT[8192,4096] * wp[4096,4096]^T + bp.
// grid = 512 blocks (32 mt x 16 nt), XCD-chunked swizzle.
// ---------------------------------------------------------------------------
__global__ __launch_bounds__(512, 2) void proj_gemm256_kernel(
    const bf16_t* __restrict__ attnT, const bf16_t* __restrict__ wpb,
    const float* __restrict__ bp, float* __restrict__ out)
{
    const int bid = blockIdx.x;
    const int wg  = (bid & 7) * 64 + (bid >> 3);    // 512 = 8 * 64, bijective
    const int mt  = wg >> 4;
    const int nt  = wg & 15;
    const int Mb  = mt << 8;
    const int Nb  = nt << 8;

    f32x4 acc[8][4] = {};
    gemm256_core(attnT + (size_t)Mb * NC, wpb + (size_t)Nb * NC, acc);

    const int tid = threadIdx.x, lane = tid & 63, w = tid >> 6;
    const int wr = w >> 2, wc = w & 3;
    const int colb = Nb + wc * 64 + (lane & 15);
    const int rowb = Mb + wr * 128 + ((lane >> 4) << 2);
    float bias[4];
    #pragma unroll
    for (int n = 0; n < 4; ++n) bias[n] = bp[colb + n * 16];
    #pragma unroll
    for (int i = 0; i < 8; ++i)
        #pragma unroll
        for (int r = 0; r < 4; ++r) {
            const size_t m = (size_t)(rowb + i * 16 + r);
            #pragma unroll
            for (int n = 0; n < 4; ++n)
                out[m * NC + colb + n * 16] = acc[i][n][r] + bias[n];
        }
}

// ---------------------------------------------------------------------------
// MFMA attention per (b,h): S = scale*Q*K^T (MFMA) -> column softmax (query
// axis, fp32) -> O^T[s][t] = sum_u vT[s][u] * P[t][u] (MFMA).
// Writes attnT[b][s][h*T+t] bf16. LDS: 8K As + 8K Bs + 34K S = 50 KB.
// ---------------------------------------------------------------------------
__global__ __launch_bounds__(256) void attn_mfma_kernel(
    const bf16_t* __restrict__ q, const bf16_t* __restrict__ k,
    const bf16_t* __restrict__ vT, bf16_t* __restrict__ attnT)
{
    __shared__ __align__(16) bf16_t As[128 * 32];
    __shared__ __align__(16) bf16_t Bs[128 * 32];
    __shared__ __align__(16) bf16_t S[NT * SLD];

    const int bh = blockIdx.x;
    const int b = bh >> 5, h = bh & 31;
    const bf16_t* Q  = q  + (size_t)bh * NT * NHS;
    const bf16_t* K  = k  + (size_t)bh * NT * NHS;
    const bf16_t* VT = vT + (size_t)bh * NT * NHS;

    const int tid  = threadIdx.x;
    const int lane = tid & 63;
    const int wave = tid >> 6;
    const int wr = (wave >> 1) * 64;
    const int wc = (wave & 1) * 64;
    const int srow = tid >> 2;
    const int scol = (tid & 3) * 8;
    const int m0 = wr + (lane & 15);
    const int n0 = wc + (lane & 15);
    const int kq = (lane >> 4) * 8;
    const int rbase = wr + (lane >> 4) * 4;

    f32x4 acc[4][4] = {};

    // Phase 1: S = scale * Q K^T  (contraction over head-dim, 4 steps of 32)
    for (int k0 = 0; k0 < NHS; k0 += 32) {
        load_lds16(Q + (size_t)srow        * NHS + k0 + scol, &As[srow * 32 + scol]);
        load_lds16(Q + (size_t)(srow + 64) * NHS + k0 + scol, &As[(srow + 64) * 32 + scol]);
        load_lds16(K + (size_t)srow        * NHS + k0 + scol, &Bs[srow * 32 + scol]);
        load_lds16(K + (size_t)(srow + 64) * NHS + k0 + scol, &Bs[(srow + 64) * 32 + scol]);
        __syncthreads();
        bf16x8 af[4], bfr[4];
        #pragma unroll
        for (int i = 0; i < 4; ++i) af[i]  = *(const bf16x8*)&As[(m0 + i * 16) * 32 + kq];
        #pragma unroll
        for (int j = 0; j < 4; ++j) bfr[j] = *(const bf16x8*)&Bs[(n0 + j * 16) * 32 + kq];
        #pragma unroll
        for (int i = 0; i < 4; ++i)
            #pragma unroll
            for (int j = 0; j < 4; ++j)
                acc[i][j] = __builtin_amdgcn_mfma_f32_16x16x32_bf16(af[i], bfr[j], acc[i][j], 0, 0, 0);
        __syncthreads();
    }
    // Store S[t][u] = scale * acc (bf16, ld = SLD)
    #pragma unroll
    for (int i = 0; i < 4; ++i)
        #pragma unroll
        for (int j = 0; j < 4; ++j)
            #pragma unroll
            for (int r = 0; r < 4; ++r)
                S[(rbase + i * 16 + r) * SLD + wc + j * 16 + (lane & 15)] =
                    (bf16_t)(acc[i][j][r] * SCALE);
    __syncthreads();

    // Phase 2: softmax over t (query axis) per column u; single fp32 rounding
    if (tid < NT) {
        const int u = tid;
        float m = -1e30f;
        for (int t = 0; t < NT; ++t) m = fmaxf(m, (float)S[t * SLD + u]);
        float sum = 0.f;
        for (int t = 0; t < NT; ++t) sum += __expf((float)S[t * SLD + u] - m);
        const float inv = 1.0f / sum;
        for (int t = 0; t < NT; ++t)
            S[t * SLD + u] = (bf16_t)(__expf((float)S[t * SLD + u] - m) * inv);
    }
    __syncthreads();

    // Phase 3: O^T[s][t] = sum_u VT[s][u] * P[t][u]; A=VT (global), BT=P (LDS)
    #pragma unroll
    for (int i = 0; i < 4; ++i)
        #pragma unroll
        for (int j = 0; j < 4; ++j)
            acc[i][j] = (f32x4)(0.0f);

    for (int k0 = 0; k0 < NT; k0 += 32) {
        load_lds16(VT + (size_t)srow        * NT + k0 + scol, &As[srow * 32 + scol]);
        load_lds16(VT + (size_t)(srow + 64) * NT + k0 + scol, &As[(srow + 64) * 32 + scol]);
        __syncthreads();
        bf16x8 af[4], bfr[4];
        #pragma unroll
        for (int i = 0; i < 4; ++i) af[i]  = *(const bf16x8*)&As[(m0 + i * 16) * 32 + kq];
        #pragma unroll
        for (int j = 0; j < 4; ++j) bfr[j] = *(const bf16x8*)&S[(n0 + j * 16) * SLD + k0 + kq];
        #pragma unroll
        for (int i = 0; i < 4; ++i)
            #pragma unroll
            for (int j = 0; j < 4; ++j)
                acc[i][j] = __builtin_amdgcn_mfma_f32_16x16x32_bf16(af[i], bfr[j], acc[i][j], 0, 0, 0);
        __syncthreads();
    }
    // Epilogue: D[s][t] -> attnT[b][s][h*T + t]
    bf16_t* AT = attnT + (size_t)b * NHS * NC + h * NT;
    #pragma unroll
    for (int i = 0; i < 4; ++i)
        #pragma unroll
        for (int j = 0; j < 4; ++j)
            #pragma unroll
            for (int r = 0; r < 4; ++r)
                AT[(size_t)(rbase + i * 16 + r) * NC + wc + j * 16 + (lane & 15)] =
                    (bf16_t)acc[i][j][r];
}

// ---------------------------------------------------------------------------
extern "C" void kernel_launch(void* const* d_in, const int* in_sizes, int n_in,
                              void* d_out, int out_size, void* d_ws, size_t ws_size,
                              hipStream_t stream) {
    const float* x  = (const float*)d_in[0];
    const float* wq = (const float*)d_in[1];
    const float* wk = (const float*)d_in[2];
    const float* wv = (const float*)d_in[3];
    const float* wp = (const float*)d_in[4];
    const float* bp = (const float*)d_in[5];
    float* out = (float*)d_out;

    const size_t NX = (size_t)NB * NT * NC;     // 33,554,432
    const size_t NW = (size_t)NH * NC * NHS;    // 16,777,216
    bf16_t* xb  = (bf16_t*)d_ws;
    bf16_t* wqT = xb  + NX;
    bf16_t* wkT = wqT + NW;
    bf16_t* wvT = wkT + NW;   // wqT|wkT|wvT are contiguous = Wcat[12288][4096]
    bf16_t* wpb = wvT + NW;
    bf16_t* qb  = wpb + NW;
    bf16_t* kb  = qb  + NX;
    bf16_t* vb  = kb  + NX;   // holds vT [bh][s][u]
    bf16_t* atT = vb  + NX;   // [8192][4096] == [b][s][e]

    cvt_bf16_kernel<<<(int)(NX / 8 / 256), 256, 0, stream>>>(x, xb, (int)(NX / 8));
    cvt_w_transpose_kernel<<<dim3(4096, 3), 256, 0, stream>>>(wq, wk, wv, wqT, wkT, wvT);
    cvt_bf16_kernel<<<(int)(NW / 8 / 256), 256, 0, stream>>>(wp, wpb, (int)(NW / 8));

    qkv_gemm256_kernel<<<1536, 512, 0, stream>>>(xb, wqT, qb, kb, vb);
    attn_mfma_kernel<<<NB * NH, 256, 0, stream>>>(qb, kb, vb, atT);
    proj_gemm256_kernel<<<512, 512, 0, stream>>>(atT, wpb, bp, out);
}